// Round 1
// baseline (963.676 us; speedup 1.0000x reference)
//
#include <hip/hip_runtime.h>
#include <stdint.h>

#define F 16
#define CDIM 320
#define DDIM 4096
#define BB 2
#define NHEADS 8
#define DH 40
#define NSEQ (BB*DDIM)        // 8192 sequences
#define WPB 4                 // waves (sequences) per block
#define THREADS (WPB*64)
#define NT (CDIM/16)          // 20 n-tiles
#define KS (CDIM/32)          // 10 k-steps

typedef __attribute__((ext_vector_type(8))) short short8;
typedef __attribute__((ext_vector_type(4))) float f32x4;

__device__ __forceinline__ unsigned short f2bf(float f) {
    union { float f; uint32_t u; } v; v.f = f;
    uint32_t r = v.u + 0x7FFFu + ((v.u >> 16) & 1u);   // RTNE
    return (unsigned short)(r >> 16);
}
__device__ __forceinline__ float bf2f(unsigned short h) {
    union { uint32_t u; float f; } v; v.u = ((uint32_t)h) << 16;
    return v.f;
}
// XOR swizzle inside a [16][320] bf16 row-major tile (row stride 640 B).
// Moves 16B chunks so that b128 reads across rows hit distinct banks.
__device__ __forceinline__ int swz(int row, int b) {
    return row * 640 + (b ^ ((row & 7) << 4));
}

__global__ __launch_bounds__(THREADS, 1)
void temporal_attn_kernel(const float* __restrict__ hs,
                          const float* __restrict__ Wq,
                          const float* __restrict__ Wk,
                          const float* __restrict__ Wv,
                          const float* __restrict__ Wo,
                          const float* __restrict__ bo,
                          float* __restrict__ out)
{
    extern __shared__ __align__(16) char smem[];
    // [0, 30720): 3 weight slabs [16][320] bf16 (Q,K,V / reused for O)
    // [30720 + wave*30720, +30720): per-wave qbuf/kbuf/vbuf [16][320] bf16
    const int tid  = threadIdx.x;
    const int lane = tid & 63;
    const int wave = tid >> 6;
    const int g    = lane >> 4;    // lane group 0..3
    const int lr   = lane & 15;    // row/col-in-tile index

    const int seq = blockIdx.x * WPB + wave;
    const int bi  = seq >> 12;          // / 4096
    const int di  = seq & (DDIM - 1);

    char* const wslab = smem;
    char* const mybuf = smem + 3*10240 + wave * 3*10240;
    char* const qbuf  = mybuf;
    char* const kbuf  = mybuf + 10240;
    char* const vbuf  = mybuf + 20480;

    // ---- load x fragments for this wave's sequence, add PE, convert bf16 ----
    // A-fragment for mfma_16x16x32: lane holds x[lr][g*8 + 32*ks .. +7]
    const float* xrow = hs + ((size_t)(bi * F + lr) * DDIM + di) * CDIM;
    short8 axk[KS];
#pragma unroll
    for (int ks = 0; ks < KS; ++ks) {
        const int k0 = ks * 32 + g * 8;
        const f32x4 a = *(const f32x4*)(xrow + k0);
        const f32x4 b = *(const f32x4*)(xrow + k0 + 4);
        float xv[8] = {a[0],a[1],a[2],a[3],b[0],b[1],b[2],b[3]};
#pragma unroll
        for (int jj = 0; jj < 4; ++jj) {
            const float c0 = (float)(k0 + 2*jj);
            const float dv = __expf(c0 * -0.028782313662425575f); // -ln(1e4)/320
            const float ang = (float)lr * dv;                      // pos = frame = lr
            xv[2*jj]   += __sinf(ang);
            xv[2*jj+1] += __cosf(ang);
        }
        short8 t;
#pragma unroll
        for (int j = 0; j < 8; ++j) t[j] = (short)f2bf(xv[j]);
        axk[ks] = t;
    }

    // ---- QKV projections: q/k/v = (x+pe) @ W.T via MFMA ----
#pragma unroll 1
    for (int nt = 0; nt < NT; ++nt) {
        __syncthreads();   // previous tile's B-frag reads done before restage
        // cooperative stage: rows nt*16..+15 of Wq,Wk,Wv, all 320 k, fp32->bf16
        for (int t = tid; t < 3*16*40; t += THREADS) {
            const int p   = t / 640;
            const int rem = t - p*640;
            const int row = rem / 40;
            const int k8  = rem - row*40;
            const float* W = (p == 0) ? Wq : (p == 1) ? Wk : Wv;
            const float* src = W + (size_t)(nt*16 + row) * CDIM + k8*8;
            const f32x4 a = *(const f32x4*)(src);
            const f32x4 b = *(const f32x4*)(src + 4);
            float vals[8] = {a[0],a[1],a[2],a[3],b[0],b[1],b[2],b[3]};
            short8 pk;
#pragma unroll
            for (int j = 0; j < 8; ++j) pk[j] = (short)f2bf(vals[j]);
            *(short8*)(wslab + p*10240 + swz(row, k8*16)) = pk;
        }
        __syncthreads();
        f32x4 aq = {0,0,0,0}, ak = {0,0,0,0}, av = {0,0,0,0};
#pragma unroll
        for (int ks = 0; ks < KS; ++ks) {
            const int boff = swz(lr, ks*64 + g*16); // B-frag: W[nt*16+lr][32ks+8g..]
            short8 bq = *(const short8*)(wslab + boff);
            short8 bk = *(const short8*)(wslab + 10240 + boff);
            short8 bv = *(const short8*)(wslab + 20480 + boff);
            aq = __builtin_amdgcn_mfma_f32_16x16x32_bf16(axk[ks], bq, aq, 0, 0, 0);
            ak = __builtin_amdgcn_mfma_f32_16x16x32_bf16(axk[ks], bk, ak, 0, 0, 0);
            av = __builtin_amdgcn_mfma_f32_16x16x32_bf16(axk[ks], bv, av, 0, 0, 0);
        }
        // C-frag epilogue: D[row=g*4+r][col=nt*16+lr] -> per-wave LDS (bf16)
#pragma unroll
        for (int r = 0; r < 4; ++r) {
            const int row = g*4 + r;
            const int cb  = (nt*16 + lr) * 2;
            *(short*)(qbuf + swz(row, cb)) = (short)f2bf(aq[r]);
            *(short*)(kbuf + swz(row, cb)) = (short)f2bf(ak[r]);
            *(short*)(vbuf + swz(row, cb)) = (short)f2bf(av[r]);
        }
    }

    // ---- causal attention, VALU, per wave; lane = (q-row=lr, head=g+4*h2) ----
    const float scale = 0.15811388300841897f;  // 40^-0.5
    const int qr = lr;
#pragma unroll 1
    for (int h2 = 0; h2 < 2; ++h2) {
        const int h  = g + 4*h2;
        const int cb = h * DH * 2;   // byte offset of this head in a row
        float qv[DH];
#pragma unroll
        for (int j5 = 0; j5 < 5; ++j5) {
            short8 t = *(const short8*)(qbuf + swz(qr, cb + j5*16));
#pragma unroll
            for (int j = 0; j < 8; ++j) qv[j5*8+j] = bf2f((unsigned short)t[j]);
        }
        float s[F];
#pragma unroll
        for (int kk = 0; kk < F; ++kk) {
            float dot = 0.f;
#pragma unroll
            for (int j5 = 0; j5 < 5; ++j5) {
                short8 t = *(const short8*)(kbuf + swz(kk, cb + j5*16));
#pragma unroll
                for (int j = 0; j < 8; ++j) dot += qv[j5*8+j] * bf2f((unsigned short)t[j]);
            }
            s[kk] = (kk <= qr) ? dot * scale : -1e30f;
        }
        float m = s[0];
#pragma unroll
        for (int kk = 1; kk < F; ++kk) m = fmaxf(m, s[kk]);
        float p[F]; float sum = 0.f;
#pragma unroll
        for (int kk = 0; kk < F; ++kk) { p[kk] = __expf(s[kk] - m); sum += p[kk]; }
        const float inv = 1.f / sum;
        float acc[DH];
#pragma unroll
        for (int dd = 0; dd < DH; ++dd) acc[dd] = 0.f;
#pragma unroll
        for (int kk = 0; kk < F; ++kk) {
            const float pk = p[kk] * inv;
#pragma unroll
            for (int j5 = 0; j5 < 5; ++j5) {
                short8 t = *(const short8*)(vbuf + swz(kk, cb + j5*16));
#pragma unroll
                for (int j = 0; j < 8; ++j) acc[j5*8+j] += pk * bf2f((unsigned short)t[j]);
            }
        }
        // attention-out overwrites qbuf (this lane reads only its own region)
#pragma unroll
        for (int j5 = 0; j5 < 5; ++j5) {
            short8 t;
#pragma unroll
            for (int j = 0; j < 8; ++j) t[j] = (short)f2bf(acc[j5*8+j]);
            *(short8*)(qbuf + swz(qr, cb + j5*16)) = t;
        }
    }

    // ---- output projection: out = ao @ Wo.T + bo ----
    short8 aof[KS];
#pragma unroll
    for (int ks = 0; ks < KS; ++ks)
        aof[ks] = *(const short8*)(qbuf + swz(lr, ks*64 + g*16));

#pragma unroll 1
    for (int nt = 0; nt < NT; ++nt) {
        __syncthreads();
        for (int t = tid; t < 640; t += THREADS) {
            const int row = t / 40;
            const int k8  = t - row*40;
            const float* src = Wo + (size_t)(nt*16 + row) * CDIM + k8*8;
            const f32x4 a = *(const f32x4*)(src);
            const f32x4 b = *(const f32x4*)(src + 4);
            float vals[8] = {a[0],a[1],a[2],a[3],b[0],b[1],b[2],b[3]};
            short8 pk;
#pragma unroll
            for (int j = 0; j < 8; ++j) pk[j] = (short)f2bf(vals[j]);
            *(short8*)(wslab + swz(row, k8*16)) = pk;
        }
        __syncthreads();
        f32x4 acc = {0,0,0,0};
#pragma unroll
        for (int ks = 0; ks < KS; ++ks) {
            short8 b = *(const short8*)(wslab + swz(lr, ks*64 + g*16));
            acc = __builtin_amdgcn_mfma_f32_16x16x32_bf16(aof[ks], b, acc, 0, 0, 0);
        }
        const int col = nt*16 + lr;
        const float bias = bo[col];
#pragma unroll
        for (int r = 0; r < 4; ++r) {
            const int row = g*4 + r;   // = frame index
            out[((size_t)(bi*F + row) * DDIM + di) * CDIM + col] = acc[r] + bias;
        }
    }
}

extern "C" void kernel_launch(void* const* d_in, const int* in_sizes, int n_in,
                              void* d_out, int out_size, void* d_ws, size_t ws_size,
                              hipStream_t stream) {
    const float* hs = (const float*)d_in[0];
    const float* Wq = (const float*)d_in[1];
    const float* Wk = (const float*)d_in[2];
    const float* Wv = (const float*)d_in[3];
    const float* Wo = (const float*)d_in[4];
    const float* bo = (const float*)d_in[5];
    float* out = (float*)d_out;
    const int lds = 3*10240 + WPB*3*10240;   // 153600 B dynamic LDS
    (void)hipFuncSetAttribute((const void*)temporal_attn_kernel,
                              hipFuncAttributeMaxDynamicSharedMemorySize, lds);
    temporal_attn_kernel<<<dim3(NSEQ/WPB), dim3(THREADS), lds, stream>>>(
        hs, Wq, Wk, Wv, Wo, bo, out);
}

// Round 2
// 372.505 us; speedup vs baseline: 2.5870x; 2.5870x over previous
//
#include <hip/hip_runtime.h>
#include <stdint.h>

#define F 16
#define CDIM 320
#define DDIM 4096
#define NSEQ 8192
#define WPB 4
#define THREADS 256
#define NT 20
#define KS 10

typedef __attribute__((ext_vector_type(8))) short short8;
typedef __attribute__((ext_vector_type(4))) float f32x4;

__device__ __forceinline__ unsigned short f2bf(float f) {
    union { float f; uint32_t u; } v; v.f = f;
    uint32_t r = v.u + 0x7FFFu + ((v.u >> 16) & 1u);   // RTNE
    return (unsigned short)(r >> 16);
}
__device__ __forceinline__ float bf2f(unsigned short h) {
    union { uint32_t u; float f; } v; v.u = ((uint32_t)h) << 16;
    return v.f;
}
// XOR swizzle inside a [16][320] bf16 row-major tile (row stride 640 B)
__device__ __forceinline__ int swz(int row, int b) {
    return row * 640 + (b ^ ((row & 7) << 4));
}

// One-time: pack Wq/Wk/Wv/Wo (fp32 row-major [320][320]) into bf16 B-fragment
// order. Fragment (m, nt, ks) is a 1KB block: lane (g,lr) holds
// W[nt*16+lr][ks*32+g*8 .. +7]. Byte offset = ((m*NT+nt)*KS+ks)*1024 + lane*16.
__global__ __launch_bounds__(256)
void pack_weights_kernel(const float* __restrict__ Wq, const float* __restrict__ Wk,
                         const float* __restrict__ Wv, const float* __restrict__ Wo,
                         char* __restrict__ pk)
{
    const int t = blockIdx.x * 256 + threadIdx.x;
    if (t >= 4 * NT * KS * 64) return;
    const int lane = t & 63;
    const int rest = t >> 6;                 // (m*NT+nt)*KS+ks
    const int ks = rest % KS;
    const int nt = (rest / KS) % NT;
    const int m  = rest / (KS * NT);
    const float* W = (m == 0) ? Wq : (m == 1) ? Wk : (m == 2) ? Wv : Wo;
    const int g = lane >> 4, lr = lane & 15;
    const float* src = W + (size_t)(nt * 16 + lr) * CDIM + ks * 32 + g * 8;
    const f32x4 a = *(const f32x4*)src;
    const f32x4 b = *(const f32x4*)(src + 4);
    float vals[8] = {a[0], a[1], a[2], a[3], b[0], b[1], b[2], b[3]};
    short8 o;
#pragma unroll
    for (int j = 0; j < 8; ++j) o[j] = (short)f2bf(vals[j]);
    *(short8*)(pk + (size_t)t * 16) = o;
}

__global__ __launch_bounds__(THREADS, 2)
void temporal_attn_kernel(const float* __restrict__ hs,
                          const char* __restrict__ wpk,
                          const float* __restrict__ bo,
                          float* __restrict__ out)
{
    extern __shared__ __align__(16) char smem[];
    // per-wave only: kbuf [16][320] bf16 (10240 B) + vbuf (10240 B). No
    // cross-wave sharing -> NO __syncthreads anywhere.
    const int tid  = threadIdx.x;
    const int lane = tid & 63;
    const int wave = tid >> 6;
    const int g    = lane >> 4;
    const int lr   = lane & 15;

    const int seq = blockIdx.x * WPB + wave;
    const int bi  = seq >> 12;
    const int di  = seq & (DDIM - 1);

    char* const kbuf = smem + wave * 20480;
    char* const vbuf = kbuf + 10240;
    const char* const wl = wpk + lane * 16;

    // ---- load x rows, add PE, convert to bf16 A-fragments ----
    const float* xrow = hs + ((size_t)(bi * F + lr) * DDIM + di) * CDIM;
    short8 axk[KS];
#pragma unroll
    for (int ks = 0; ks < KS; ++ks) {
        const int k0 = ks * 32 + g * 8;
        const f32x4 a = __builtin_nontemporal_load((const f32x4*)(xrow + k0));
        const f32x4 b = __builtin_nontemporal_load((const f32x4*)(xrow + k0 + 4));
        float xv[8] = {a[0], a[1], a[2], a[3], b[0], b[1], b[2], b[3]};
#pragma unroll
        for (int jj = 0; jj < 4; ++jj) {
            const float c0 = (float)(k0 + 2 * jj);
            const float dv = __expf(c0 * -0.028782313662425575f); // -ln(1e4)/320
            const float ang = (float)lr * dv;                      // pos = frame
            xv[2 * jj]     += __sinf(ang);
            xv[2 * jj + 1] += __cosf(ang);
        }
        short8 t;
#pragma unroll
        for (int j = 0; j < 8; ++j) t[j] = (short)f2bf(xv[j]);
        axk[ks] = t;
    }

    // ---- projection pass: dst[row][col] = sum_k x[row][k] * W[col][k] ----
    auto proj = [&](int m, char* dst) {
#pragma unroll 2
        for (int nt = 0; nt < NT; ++nt) {
            f32x4 acc = {0.f, 0.f, 0.f, 0.f};
#pragma unroll
            for (int ks = 0; ks < KS; ++ks) {
                short8 b = *(const short8*)(wl + (size_t)((m * NT + nt) * KS + ks) * 1024);
                acc = __builtin_amdgcn_mfma_f32_16x16x32_bf16(axk[ks], b, acc, 0, 0, 0);
            }
#pragma unroll
            for (int r = 0; r < 4; ++r)
                *(short*)(dst + swz(g * 4 + r, (nt * 16 + lr) * 2)) = (short)f2bf(acc[r]);
        }
    };

    // Q -> kbuf (transient), extract q to registers, then K overwrites kbuf.
    proj(0, kbuf);
    short8 qreg[2][5];
#pragma unroll
    for (int h2 = 0; h2 < 2; ++h2)
#pragma unroll
        for (int j5 = 0; j5 < 5; ++j5)
            qreg[h2][j5] = *(const short8*)(kbuf + swz(lr, (g + 4 * h2) * 80 + j5 * 16));
    proj(1, kbuf);
    proj(2, vbuf);

    // ---- causal attention; lane = (q-row = lr, head = g + 4*h2) ----
    const float scale = 0.15811388300841897f;  // 40^-0.5
#pragma unroll 1
    for (int h2 = 0; h2 < 2; ++h2) {
        const int cb = (g + 4 * h2) * 80;   // byte offset of head in a row
        float qv[40];
#pragma unroll
        for (int j5 = 0; j5 < 5; ++j5)
#pragma unroll
            for (int j = 0; j < 8; ++j)
                qv[j5 * 8 + j] = bf2f((unsigned short)qreg[h2][j5][j]);
        float s[F];
#pragma unroll
        for (int kk = 0; kk < F; ++kk) {
            float dot = 0.f;
#pragma unroll
            for (int j5 = 0; j5 < 5; ++j5) {
                short8 t = *(const short8*)(kbuf + swz(kk, cb + j5 * 16));
#pragma unroll
                for (int j = 0; j < 8; ++j) dot += qv[j5 * 8 + j] * bf2f((unsigned short)t[j]);
            }
            s[kk] = (kk <= lr) ? dot * scale : -1e30f;
        }
        float m = s[0];
#pragma unroll
        for (int kk = 1; kk < F; ++kk) m = fmaxf(m, s[kk]);
        float p[F]; float sum = 0.f;
#pragma unroll
        for (int kk = 0; kk < F; ++kk) { p[kk] = __expf(s[kk] - m); sum += p[kk]; }
        const float inv = 1.f / sum;
        float acc[40];
#pragma unroll
        for (int dd = 0; dd < 40; ++dd) acc[dd] = 0.f;
#pragma unroll
        for (int kk = 0; kk < F; ++kk) {
            const float pk = p[kk] * inv;
#pragma unroll
            for (int j5 = 0; j5 < 5; ++j5) {
                short8 t = *(const short8*)(vbuf + swz(kk, cb + j5 * 16));
#pragma unroll
                for (int j = 0; j < 8; ++j) acc[j5 * 8 + j] += pk * bf2f((unsigned short)t[j]);
            }
        }
        // write attention-out for this head back into kbuf (head regions are
        // disjoint 16B chunks; h2=1 scores only read the h>=4 region)
#pragma unroll
        for (int j5 = 0; j5 < 5; ++j5) {
            short8 t;
#pragma unroll
            for (int j = 0; j < 8; ++j) t[j] = (short)f2bf(acc[j5 * 8 + j]);
            *(short8*)(kbuf + swz(lr, cb + j5 * 16)) = t;
        }
    }

    // ---- output projection: out = ao @ Wo.T + bo ----
    short8 aof[KS];
#pragma unroll
    for (int ks = 0; ks < KS; ++ks)
        aof[ks] = *(const short8*)(kbuf + swz(lr, ks * 64 + g * 16));

#pragma unroll 2
    for (int nt = 0; nt < NT; ++nt) {
        f32x4 acc = {0.f, 0.f, 0.f, 0.f};
#pragma unroll
        for (int ks = 0; ks < KS; ++ks) {
            short8 b = *(const short8*)(wl + (size_t)((3 * NT + nt) * KS + ks) * 1024);
            acc = __builtin_amdgcn_mfma_f32_16x16x32_bf16(aof[ks], b, acc, 0, 0, 0);
        }
        const int col = nt * 16 + lr;
        const float bias = bo[col];
#pragma unroll
        for (int r = 0; r < 4; ++r) {
            const int row = g * 4 + r;   // frame index
            __builtin_nontemporal_store(acc[r] + bias,
                out + ((size_t)(bi * F + row) * DDIM + di) * CDIM + col);
        }
    }
}

extern "C" void kernel_launch(void* const* d_in, const int* in_sizes, int n_in,
                              void* d_out, int out_size, void* d_ws, size_t ws_size,
                              hipStream_t stream) {
    const float* hs = (const float*)d_in[0];
    const float* Wq = (const float*)d_in[1];
    const float* Wk = (const float*)d_in[2];
    const float* Wv = (const float*)d_in[3];
    const float* Wo = (const float*)d_in[4];
    const float* bo = (const float*)d_in[5];
    float* out = (float*)d_out;
    char* wpk = (char*)d_ws;   // 4*200*1024 = 819200 B of packed bf16 weights

    pack_weights_kernel<<<dim3((4 * NT * KS * 64 + 255) / 256), dim3(256), 0, stream>>>(
        Wq, Wk, Wv, Wo, wpk);

    const int lds = WPB * 20480;   // 81920 B
    (void)hipFuncSetAttribute((const void*)temporal_attn_kernel,
                              hipFuncAttributeMaxDynamicSharedMemorySize, lds);
    temporal_attn_kernel<<<dim3(NSEQ / WPB), dim3(THREADS), lds, stream>>>(
        hs, wpk, bo, out);
}